// Round 12
// baseline (94.151 us; speedup 1.0000x reference)
//
#include <hip/hip_runtime.h>
#include <math.h>

// N=1024, X_DIM=HID=Y_DIM=256. 3 launches. Rules learned: no cross-block
// fences/spins (R4/R9); fire-and-forget atomics fine (R10); occupancy is the
// operative lever (R11: 2 blocks/CU -7us). This round: 4 blocks/CU via
// quartered tiles + wave-level k-split with LDS combine.
constexpr int LSB = 72;  // bf16 LDS row stride (144 B) — benign banks

typedef short bf16x8 __attribute__((ext_vector_type(8)));
typedef float f32x4  __attribute__((ext_vector_type(4)));

__device__ __forceinline__ unsigned short f2bf_rne(float f) {
    unsigned u = __float_as_uint(f);
    unsigned r = (u + 0x7fff + ((u >> 16) & 1)) >> 16;
    return (unsigned short)r;
}
__device__ __forceinline__ float bf2f(unsigned short h) {
    return __uint_as_float(((unsigned)h) << 16);
}
__device__ __forceinline__ void split4(float4 v, ushort4& hi, ushort4& lo) {
    hi.x = f2bf_rne(v.x); lo.x = f2bf_rne(v.x - bf2f(hi.x));
    hi.y = f2bf_rne(v.y); lo.y = f2bf_rne(v.y - bf2f(hi.y));
    hi.z = f2bf_rne(v.z); lo.z = f2bf_rne(v.z - bf2f(hi.z));
    hi.w = f2bf_rne(v.w); lo.w = f2bf_rne(v.w - bf2f(hi.w));
}

// ---------------------------------------------------------------------------
// K1: grid 1040. bids 0..15: moment partials (16 sets of column sums over
// 64-row chunks). bids 16..1039: layer-1 GEMM, 32x16 tile, K=256.
// GEMM decode: g=bid-16, head=g&1, ct=(g>>1)&15 (16 cols), rt=g>>5 (32 rows).
// Waves: mt=w&1 (16-row half), ks=w>>1 (k-half of 128). Both k-halves staged
// per 64-sub-tile; k-half partials combined via LDS Cx.
// ---------------------------------------------------------------------------
__global__ __launch_bounds__(256, 4)
void k1_layer1(const float* __restrict__ x,
               const float* __restrict__ w1m, const float* __restrict__ w1l,
               const float* __restrict__ b1m, const float* __restrict__ b1l,
               const float* __restrict__ w2m, const float* __restrict__ w2l,
               unsigned short* __restrict__ hmH, unsigned short* __restrict__ hmL,
               unsigned short* __restrict__ hlH, unsigned short* __restrict__ hlL,
               unsigned short* __restrict__ w2mH, unsigned short* __restrict__ w2mL,
               unsigned short* __restrict__ w2lH, unsigned short* __restrict__ w2lL,
               const float* __restrict__ y, const float* __restrict__ z,
               float* __restrict__ pA1, float* __restrict__ pB1,
               float* __restrict__ rowAcc) {
    const int bid = blockIdx.x, t = threadIdx.x;

    if (bid < 16) {   // moment partial block: rows [bid*64, +64), thread=col
        float sA = 0.f, sB = 0.f;
        int base = bid * 64 * 256 + t;
        for (int j = 0; j < 64; j++) {
            float yv = y[base + j * 256];
            float zv = z[base + j * 256];
            sA += yv * yv + zv * zv;
            sB += yv + zv;
        }
        pA1[bid * 256 + t] = sA;
        pB1[bid * 256 + t] = sB;
        return;
    }

    const int g = bid - 16;
    const int head = g & 1, ct = (g >> 1) & 15, rt = g >> 5;
    const int rowBase = rt * 32, colBase = ct * 16;
    const int w = t >> 6, lane = t & 63, quad = lane >> 4, mr = lane & 15;
    const int mt = w & 1, ks = w >> 1;

    const float* Bw   = head ? w1l : w1m;
    const float* bias = head ? b1l : b1m;
    unsigned short* CH = head ? hlH : hmH;
    unsigned short* CL = head ? hlL : hmL;

    __shared__ __align__(16) unsigned short Ast[2][2][32][LSB]; // [khalf][hi/lo]
    __shared__ __align__(16) unsigned short Bst[2][2][16][LSB];
    __shared__ float Cx[2][16][17];

    f32x4 acc = {0.f, 0.f, 0.f, 0.f};

    for (int sub = 0; sub < 2; sub++) {
        // stage A (32 rows) and B (16 rows) for BOTH k-halves of this sub
#pragma unroll
        for (int p = 0; p < 4; p++) {       // A: 2 halves x 32 x 16 = 1024 float4
            int idx = p * 256 + t;
            int q = idx >> 9, r = (idx >> 4) & 31, k4 = idx & 15;
            float4 av = *(const float4*)&x[(rowBase + r) * 256 + q * 128 + sub * 64 + k4 * 4];
            ushort4 h4, l4;
            split4(av, h4, l4);
            *(ushort4*)&Ast[q][0][r][k4 * 4] = h4;
            *(ushort4*)&Ast[q][1][r][k4 * 4] = l4;
        }
#pragma unroll
        for (int p = 0; p < 2; p++) {       // B: 2 halves x 16 x 16 = 512 float4
            int idx = p * 256 + t;
            int q = idx >> 8, r = (idx >> 4) & 15, k4 = idx & 15;
            float4 bv = *(const float4*)&Bw[(colBase + r) * 256 + q * 128 + sub * 64 + k4 * 4];
            ushort4 h4, l4;
            split4(bv, h4, l4);
            *(ushort4*)&Bst[q][0][r][k4 * 4] = h4;
            *(ushort4*)&Bst[q][1][r][k4 * 4] = l4;
        }
        __syncthreads();

#pragma unroll
        for (int kk = 0; kk < 64; kk += 32) {
            int ko = kk + quad * 8;
            bf16x8 ah = *(const bf16x8*)&Ast[ks][0][mt * 16 + mr][ko];
            bf16x8 al = *(const bf16x8*)&Ast[ks][1][mt * 16 + mr][ko];
            bf16x8 bh = *(const bf16x8*)&Bst[ks][0][mr][ko];
            bf16x8 bl = *(const bf16x8*)&Bst[ks][1][mr][ko];
            acc = __builtin_amdgcn_mfma_f32_16x16x32_bf16(ah, bh, acc, 0, 0, 0);
            acc = __builtin_amdgcn_mfma_f32_16x16x32_bf16(ah, bl, acc, 0, 0, 0);
            acc = __builtin_amdgcn_mfma_f32_16x16x32_bf16(al, bh, acc, 0, 0, 0);
        }
        __syncthreads();
    }

    // combine k-halves: ks=1 waves post partials; ks=0 waves finish + store
    if (ks == 1) {
#pragma unroll
        for (int reg = 0; reg < 4; reg++)
            Cx[mt][quad * 4 + reg][mr] = acc[reg];
    }
    __syncthreads();
    if (ks == 0) {
        int cg = colBase + mr;
        float bb = bias[cg];
#pragma unroll
        for (int reg = 0; reg < 4; reg++) {
            int rg = rowBase + mt * 16 + quad * 4 + reg;
            float v = fmaxf(acc[reg] + Cx[mt][quad * 4 + reg][mr] + bb, 0.f);
            unsigned short hi = f2bf_rne(v);
            CH[rg * 256 + cg] = hi;
            CL[rg * 256 + cg] = f2bf_rne(v - bf2f(hi));
        }
    }

    // w2 pre-split: GEMM blocks g<256 cover 256x256, 1 elem/thread
    if (g < 256) {
        int off = g * 256 + t;
        float vm = w2m[off], vl = w2l[off];
        unsigned short h1 = f2bf_rne(vm);
        w2mH[off] = h1; w2mL[off] = f2bf_rne(vm - bf2f(h1));
        unsigned short h2 = f2bf_rne(vl);
        w2lH[off] = h2; w2lL[off] = f2bf_rne(vl - bf2f(h2));
    }

    // zero rowAcc (consumed by K2 across the kernel boundary)
    if (g < 4) rowAcc[g * 256 + t] = 0.f;
}

// ---------------------------------------------------------------------------
// K2: layer-2 GEMM, both heads, 16x16 patch, K=256, conversion-free +
// in-block CLUB epilogue. 1024 blocks = 64 rt x 16 ct.
// Waves: h=w&1 (head), ks=w>>1 (k-half). LDS flat-aliased to fit 4 blocks/CU.
// ---------------------------------------------------------------------------
__global__ __launch_bounds__(256, 4)
void k2_fused(const unsigned short* __restrict__ hmH, const unsigned short* __restrict__ hmL,
              const unsigned short* __restrict__ hlH, const unsigned short* __restrict__ hlL,
              const unsigned short* __restrict__ w2mH, const unsigned short* __restrict__ w2mL,
              const unsigned short* __restrict__ w2lH, const unsigned short* __restrict__ w2lL,
              const float* __restrict__ b2m, const float* __restrict__ b2l,
              const float* __restrict__ y, const float* __restrict__ z,
              const float* __restrict__ pA1, const float* __restrict__ pB1,
              float* __restrict__ rowAcc) {
    const int bid = blockIdx.x, t = threadIdx.x;
    const int rt = bid >> 4, ct = bid & 15;
    const int rowBase = rt * 16, colBase = ct * 16;
    const int w = t >> 6, lane = t & 63, quad = lane >> 4, mr = lane & 15;
    const int h = w & 1, ks = w >> 1;

    // flat LDS: staging (36864) + CxP (2176) + mAf/mBf (128); moment-fold
    // scratch aliases the staging region (used strictly before staging).
    __shared__ __align__(16) char smem[39232];
    auto Ast = (unsigned short (*)[4][16][LSB])(smem);           // [khalf][plane]
    auto Bst = (unsigned short (*)[4][16][LSB])(smem + 18432);
    auto CxP = (float (*)[16][17])(smem + 36864);                // [head]
    float* mAf = (float*)(smem + 39040);
    float* mBf = (float*)(smem + 39104);
    float (*partA)[16] = (float (*)[16])(smem);                  // alias, pre-staging
    float (*partB)[16] = (float (*)[16])(smem + 1024);

    const unsigned short* Aarr[4] = {hmH, hmL, hlH, hlL};
    const unsigned short* Barr[4] = {w2mH, w2mL, w2lH, w2lL};

    // ---- moment fold: 16 partial sets -> means for this block's 16 cols ----
    {
        int s = t >> 4, c = t & 15;
        partA[s][c] = pA1[s * 256 + colBase + c];
        partB[s][c] = pB1[s * 256 + colBase + c];
    }
    __syncthreads();
    if (t < 16) {
        float sA = 0.f, sB = 0.f;
#pragma unroll
        for (int s = 0; s < 16; s++) { sA += partA[s][t]; sB += partB[s][t]; }
        mAf[t] = sA * (1.f / 1024.f);
        mBf[t] = sB * (1.f / 1024.f);
    }
    __syncthreads();   // part region is dead; staging may overwrite

    f32x4 acc = {0.f, 0.f, 0.f, 0.f};

    for (int sub = 0; sub < 2; sub++) {
        // stage A and B (4 planes each, 16 rows, both k-halves): 8 iters each
#pragma unroll
        for (int p = 0; p < 8; p++) {
            int idx = p * 256 + t;
            int hp = idx >> 9, q = (idx >> 8) & 1, r = (idx >> 4) & 15, k4 = idx & 15;
            *(ushort4*)&Ast[q][hp][r][k4 * 4] =
                *(const ushort4*)&Aarr[hp][(rowBase + r) * 256 + q * 128 + sub * 64 + k4 * 4];
            *(ushort4*)&Bst[q][hp][r][k4 * 4] =
                *(const ushort4*)&Barr[hp][(colBase + r) * 256 + q * 128 + sub * 64 + k4 * 4];
        }
        __syncthreads();

#pragma unroll
        for (int kk = 0; kk < 64; kk += 32) {
            int ko = kk + quad * 8;
            bf16x8 ah = *(const bf16x8*)&Ast[ks][h * 2 + 0][mr][ko];
            bf16x8 al = *(const bf16x8*)&Ast[ks][h * 2 + 1][mr][ko];
            bf16x8 bh = *(const bf16x8*)&Bst[ks][h * 2 + 0][mr][ko];
            bf16x8 bl = *(const bf16x8*)&Bst[ks][h * 2 + 1][mr][ko];
            acc = __builtin_amdgcn_mfma_f32_16x16x32_bf16(ah, bh, acc, 0, 0, 0);
            acc = __builtin_amdgcn_mfma_f32_16x16x32_bf16(ah, bl, acc, 0, 0, 0);
            acc = __builtin_amdgcn_mfma_f32_16x16x32_bf16(al, bh, acc, 0, 0, 0);
        }
        __syncthreads();
    }

    // combine k-halves into CxP (C/D layout: col=lane&15, row=quad*4+reg)
    if (ks == 1) {
#pragma unroll
        for (int reg = 0; reg < 4; reg++)
            CxP[h][quad * 4 + reg][mr] = acc[reg];
    }
    __syncthreads();
    if (ks == 0) {
        float bb = (h ? b2l : b2m)[colBase + mr];
#pragma unroll
        for (int reg = 0; reg < 4; reg++)
            CxP[h][quad * 4 + reg][mr] += acc[reg] + bb;   // each cell one owner
    }
    __syncthreads();

    // ---- in-block CLUB epilogue: 16x16 patch; reduce 16 cols -> rowAcc ----
    {
        int row = t >> 4, col = t & 15;
        int o = (rowBase + row) * 256 + colBase + col;
        float m  = CxP[0][row][col];
        float lv = tanhf(CxP[1][row][col]);
        float iv = 0.5f * expf(-lv);      // 1/(2*exp(logvar))
        float yv = y[o];
        float zv = z[o];
        float Mt = mAf[col] - 2.f * m * mBf[col] + 2.f * m * m;
        float dy = m - yv, dz = m - zv;
        float term = iv * (Mt - dy * dy - dz * dz);
#pragma unroll
        for (int msk = 8; msk; msk >>= 1)
            term += __shfl_xor(term, msk, 16);
        if (col == 0) atomicAdd(&rowAcc[rowBase + row], term);  // no fence
    }
}

// ---------------------------------------------------------------------------
// K3: 1 block. out = mean_i relu(rowAcc[i]).
// ---------------------------------------------------------------------------
__global__ __launch_bounds__(256)
void k3_final(const float* __restrict__ rowAcc, float* __restrict__ out) {
    __shared__ float red[4];
    int t = threadIdx.x, lane = t & 63, wave = t >> 6;
    float v = 0.f;
#pragma unroll
    for (int p = 0; p < 4; p++)
        v += fmaxf(rowAcc[p * 256 + t], 0.f);
#pragma unroll
    for (int msk = 32; msk; msk >>= 1)
        v += __shfl_xor(v, msk, 64);
    if (lane == 0) red[wave] = v;
    __syncthreads();
    if (t == 0)
        out[0] = (red[0] + red[1] + red[2] + red[3]) * (1.f / 1024.f);
}

// ---------------------------------------------------------------------------
extern "C" void kernel_launch(void* const* d_in, const int* in_sizes, int n_in,
                              void* d_out, int out_size, void* d_ws, size_t ws_size,
                              hipStream_t stream) {
    const float* x   = (const float*)d_in[0];
    const float* y   = (const float*)d_in[1];
    const float* zs  = (const float*)d_in[2];
    const float* w1m = (const float*)d_in[3];
    const float* b1m = (const float*)d_in[4];
    const float* w2m = (const float*)d_in[5];
    const float* b2m = (const float*)d_in[6];
    const float* w1l = (const float*)d_in[7];
    const float* b1l = (const float*)d_in[8];
    const float* w2l = (const float*)d_in[9];
    const float* b2l = (const float*)d_in[10];
    float* out = (float*)d_out;

    char* ws = (char*)d_ws;
    float* pA1    = (float*)(ws);                      // 16x256 f32 = 16 KB
    float* pB1    = (float*)(ws + (256u << 10));       // 16 KB
    float* rowAcc = (float*)(ws + (512u << 10));       // 4 KB
    unsigned short* hmH = (unsigned short*)(ws + (1024u << 10));  // 512 KB each
    unsigned short* hmL = (unsigned short*)(ws + (1536u << 10));
    unsigned short* hlH = (unsigned short*)(ws + (2048u << 10));
    unsigned short* hlL = (unsigned short*)(ws + (2560u << 10));
    unsigned short* w2mH = (unsigned short*)(ws + (3072u << 10)); // 128 KB each
    unsigned short* w2mL = (unsigned short*)(ws + (3200u << 10));
    unsigned short* w2lH = (unsigned short*)(ws + (3328u << 10));
    unsigned short* w2lL = (unsigned short*)(ws + (3456u << 10));

    k1_layer1<<<1040, 256, 0, stream>>>(x, w1m, w1l, b1m, b1l, w2m, w2l,
                                        hmH, hmL, hlH, hlL,
                                        w2mH, w2mL, w2lH, w2lL,
                                        y, zs, pA1, pB1, rowAcc);
    k2_fused<<<1024, 256, 0, stream>>>(hmH, hmL, hlH, hlL,
                                       w2mH, w2mL, w2lH, w2lL,
                                       b2m, b2l, y, zs, pA1, pB1, rowAcc);
    k3_final<<<1, 256, 0, stream>>>(rowAcc, out);
}

// Round 13
// 90.534 us; speedup vs baseline: 1.0399x; 1.0399x over previous
//
#include <hip/hip_runtime.h>
#include <math.h>

// N=1024, X_DIM=HID=Y_DIM=256. 3 launches. Rules learned: no cross-block
// fences/spins (R4/R9); fire-and-forget atomics fine (R10); occupancy lever
// saturates at 2 blocks/CU (R11 win, R12 regression). This round: R11 base +
// cheap moment pipeline (16 dedicated partial sets instead of 256 -> K2's
// fold drops from 32 KB to 2 KB per block).
constexpr int LSB = 72;  // bf16 LDS row stride (144 B) — benign banks

typedef short bf16x8 __attribute__((ext_vector_type(8)));
typedef float f32x4  __attribute__((ext_vector_type(4)));

__device__ __forceinline__ unsigned short f2bf_rne(float f) {
    unsigned u = __float_as_uint(f);
    unsigned r = (u + 0x7fff + ((u >> 16) & 1)) >> 16;
    return (unsigned short)r;
}
__device__ __forceinline__ float bf2f(unsigned short h) {
    return __uint_as_float(((unsigned)h) << 16);
}
__device__ __forceinline__ void split4(float4 v, ushort4& hi, ushort4& lo) {
    hi.x = f2bf_rne(v.x); lo.x = f2bf_rne(v.x - bf2f(hi.x));
    hi.y = f2bf_rne(v.y); lo.y = f2bf_rne(v.y - bf2f(hi.y));
    hi.z = f2bf_rne(v.z); lo.z = f2bf_rne(v.z - bf2f(hi.z));
    hi.w = f2bf_rne(v.w); lo.w = f2bf_rne(v.w - bf2f(hi.w));
}

// ---------------------------------------------------------------------------
// K1: grid 528. bids 0..511: layer-1 GEMM, 32x32 tile, K=256 (R11 proven):
//   head=bid&1, ct=(bid>>1)&7 (32 cols), rt=bid>>4 (0..31, 32 rows);
//   wave w: mt=w&1 (16 rows), nt=w>>1 (16 cols).
// bids 512..527: moment partials over 64-row chunks (16 sets).
// ---------------------------------------------------------------------------
__global__ __launch_bounds__(256, 2)
void k1_layer1(const float* __restrict__ x,
               const float* __restrict__ w1m, const float* __restrict__ w1l,
               const float* __restrict__ b1m, const float* __restrict__ b1l,
               const float* __restrict__ w2m, const float* __restrict__ w2l,
               unsigned short* __restrict__ hmH, unsigned short* __restrict__ hmL,
               unsigned short* __restrict__ hlH, unsigned short* __restrict__ hlL,
               unsigned short* __restrict__ w2mH, unsigned short* __restrict__ w2mL,
               unsigned short* __restrict__ w2lH, unsigned short* __restrict__ w2lL,
               const float* __restrict__ y, const float* __restrict__ z,
               float* __restrict__ pA1, float* __restrict__ pB1,
               float* __restrict__ rowAcc) {
    const int bid = blockIdx.x, t = threadIdx.x;

    if (bid >= 512) {   // moment block: rows [m*64, +64), thread = column
        int m = bid - 512;
        float sA = 0.f, sB = 0.f;
        int base = m * 64 * 256 + t;
        for (int j = 0; j < 64; j++) {
            float yv = y[base + j * 256];
            float zv = z[base + j * 256];
            sA += yv * yv + zv * zv;
            sB += yv + zv;
        }
        pA1[m * 256 + t] = sA;
        pB1[m * 256 + t] = sB;
        return;
    }

    const int head = bid & 1, ct = (bid >> 1) & 7, rt = bid >> 4;
    const int rowBase = rt * 32, colBase = ct * 32;
    const int w = t >> 6, lane = t & 63, quad = lane >> 4, mr = lane & 15;
    const int mt = w & 1, nt = w >> 1;

    const float* Bw   = head ? w1l : w1m;
    const float* bias = head ? b1l : b1m;
    unsigned short* CH = head ? hlH : hmH;
    unsigned short* CL = head ? hlL : hmL;

    __shared__ __align__(16) unsigned short Ah[32][LSB], Al[32][LSB];
    __shared__ __align__(16) unsigned short Bh[32][LSB], Bl[32][LSB];

    f32x4 acc = {0.f, 0.f, 0.f, 0.f};

    for (int kt = 0; kt < 256; kt += 64) {
        // stage 32x64 fp32 tiles of A (x) and B (w1), split to bf16 hi/lo
#pragma unroll
        for (int p = 0; p < 2; p++) {
            int idx = p * 256 + t;
            int r = idx >> 4, k4 = idx & 15;
            float4 av = *(const float4*)&x[(rowBase + r) * 256 + kt + k4 * 4];
            float4 bv = *(const float4*)&Bw[(colBase + r) * 256 + kt + k4 * 4];
            ushort4 h4, l4;
            split4(av, h4, l4);
            *(ushort4*)&Ah[r][k4 * 4] = h4;
            *(ushort4*)&Al[r][k4 * 4] = l4;
            split4(bv, h4, l4);
            *(ushort4*)&Bh[r][k4 * 4] = h4;
            *(ushort4*)&Bl[r][k4 * 4] = l4;
        }
        __syncthreads();

#pragma unroll
        for (int kk = 0; kk < 64; kk += 32) {
            int ko = kk + quad * 8;
            bf16x8 ah = *(const bf16x8*)&Ah[mt * 16 + mr][ko];
            bf16x8 al = *(const bf16x8*)&Al[mt * 16 + mr][ko];
            bf16x8 bh = *(const bf16x8*)&Bh[nt * 16 + mr][ko];
            bf16x8 bl = *(const bf16x8*)&Bl[nt * 16 + mr][ko];
            acc = __builtin_amdgcn_mfma_f32_16x16x32_bf16(ah, bh, acc, 0, 0, 0);
            acc = __builtin_amdgcn_mfma_f32_16x16x32_bf16(ah, bl, acc, 0, 0, 0);
            acc = __builtin_amdgcn_mfma_f32_16x16x32_bf16(al, bh, acc, 0, 0, 0);
        }
        __syncthreads();
    }

    // bias + relu -> Dekker split -> hi/lo stores (C/D: col=lane&15, row=quad*4+reg)
    {
        int cg = colBase + nt * 16 + mr;
        float bb = bias[cg];
#pragma unroll
        for (int reg = 0; reg < 4; reg++) {
            int rg = rowBase + mt * 16 + quad * 4 + reg;
            float v = fmaxf(acc[reg] + bb, 0.f);
            unsigned short hi = f2bf_rne(v);
            CH[rg * 256 + cg] = hi;
            CL[rg * 256 + cg] = f2bf_rne(v - bf2f(hi));
        }
    }

    // w2 pre-split (blocks 0..255 cover 256x256)
    if (bid < 256) {
        int off = bid * 256 + t;
        float vm = w2m[off], vl = w2l[off];
        unsigned short h1 = f2bf_rne(vm);
        w2mH[off] = h1; w2mL[off] = f2bf_rne(vm - bf2f(h1));
        unsigned short h2 = f2bf_rne(vl);
        w2lH[off] = h2; w2lL[off] = f2bf_rne(vl - bf2f(h2));
    }

    // zero rowAcc (consumed by K2 across the kernel boundary)
    if (bid < 4) rowAcc[bid * 256 + t] = 0.f;
}

// ---------------------------------------------------------------------------
// K2: layer-2 GEMM, both heads, 32(rows)x16(cols) patch, K=256,
// conversion-free + in-block CLUB epilogue. 512 blocks = 32 rt x 16 ct.
// Wave w: head=w&1, mt=w>>1 (16 rows), single 16-col ntile. (R11 proven.)
// Moment fold now reads 16 partial sets (one load/thread).
// ---------------------------------------------------------------------------
__global__ __launch_bounds__(256, 2)
void k2_fused(const unsigned short* __restrict__ hmH, const unsigned short* __restrict__ hmL,
              const unsigned short* __restrict__ hlH, const unsigned short* __restrict__ hlL,
              const unsigned short* __restrict__ w2mH, const unsigned short* __restrict__ w2mL,
              const unsigned short* __restrict__ w2lH, const unsigned short* __restrict__ w2lL,
              const float* __restrict__ b2m, const float* __restrict__ b2l,
              const float* __restrict__ y, const float* __restrict__ z,
              const float* __restrict__ pA1, const float* __restrict__ pB1,
              float* __restrict__ rowAcc) {
    const int bid = blockIdx.x, t = threadIdx.x;
    const int rt = bid >> 4, ct = bid & 15;
    const int rowBase = rt * 32, colBase = ct * 16;
    const int w = t >> 6, lane = t & 63, quad = lane >> 4, mr = lane & 15;
    const int h = w & 1, mt = w >> 1;

    __shared__ __align__(16) unsigned short Ast[2][2][32][LSB];  // [head][hi/lo]
    __shared__ __align__(16) unsigned short Bst[2][2][16][LSB];
    __shared__ float Cx[2][32][17];
    __shared__ float partA[16][16], partB[16][16];
    __shared__ float mAf[16], mBf[16];

    const unsigned short* Aarr[4] = {hmH, hmL, hlH, hlL};
    const unsigned short* Barr[4] = {w2mH, w2mL, w2lH, w2lL};

    // ---- moment fold: 16 partial sets -> means for this block's 16 cols ----
    {
        int s = t >> 4, c = t & 15;      // one load per thread
        partA[s][c] = pA1[s * 256 + colBase + c];
        partB[s][c] = pB1[s * 256 + colBase + c];
    }
    __syncthreads();
    if (t < 16) {
        float sA = 0.f, sB = 0.f;
#pragma unroll
        for (int s = 0; s < 16; s++) { sA += partA[s][t]; sB += partB[s][t]; }
        mAf[t] = sA * (1.f / 1024.f);
        mBf[t] = sB * (1.f / 1024.f);
    }

    f32x4 acc = {0.f, 0.f, 0.f, 0.f};

    for (int kt = 0; kt < 256; kt += 64) {
#pragma unroll
        for (int hp = 0; hp < 4; hp++) {    // head*2 + (hi/lo)
            // A: 32 rows x 16 k4-units = 512 ushort4 -> 2 iters
#pragma unroll
            for (int p = 0; p < 2; p++) {
                int idx = p * 256 + t;
                int r = idx >> 4, k4 = idx & 15;
                *(ushort4*)&Ast[hp >> 1][hp & 1][r][k4 * 4] =
                    *(const ushort4*)&Aarr[hp][(rowBase + r) * 256 + kt + k4 * 4];
            }
            // B: 16 rows x 16 k4-units = 256 ushort4 -> 1 iter
            {
                int r = t >> 4, k4 = t & 15;
                *(ushort4*)&Bst[hp >> 1][hp & 1][r][k4 * 4] =
                    *(const ushort4*)&Barr[hp][(colBase + r) * 256 + kt + k4 * 4];
            }
        }
        __syncthreads();

#pragma unroll
        for (int kk = 0; kk < 64; kk += 32) {
            int ko = kk + quad * 8;
            bf16x8 ah = *(const bf16x8*)&Ast[h][0][mt * 16 + mr][ko];
            bf16x8 al = *(const bf16x8*)&Ast[h][1][mt * 16 + mr][ko];
            bf16x8 bh = *(const bf16x8*)&Bst[h][0][mr][ko];
            bf16x8 bl = *(const bf16x8*)&Bst[h][1][mr][ko];
            acc = __builtin_amdgcn_mfma_f32_16x16x32_bf16(ah, bh, acc, 0, 0, 0);
            acc = __builtin_amdgcn_mfma_f32_16x16x32_bf16(ah, bl, acc, 0, 0, 0);
            acc = __builtin_amdgcn_mfma_f32_16x16x32_bf16(al, bh, acc, 0, 0, 0);
        }
        __syncthreads();
    }

    // ---- exchange mu/lv via LDS (C/D: col=lane&15, row=quad*4+reg) ----
    {
        const float* bias = h ? b2l : b2m;
        float bb = bias[colBase + mr];
#pragma unroll
        for (int reg = 0; reg < 4; reg++)
            Cx[h][mt * 16 + quad * 4 + reg][mr] = acc[reg] + bb;
    }
    __syncthreads();

    // ---- in-block CLUB epilogue: 32x16 patch; reduce 16 cols -> rowAcc ----
    {
        int col = t & 15, rg = t >> 4;        // rg 0..15, 2 rows each
        int gcol = colBase + col;
        float mA = mAf[col], mB = mBf[col];
#pragma unroll
        for (int rr = 0; rr < 2; rr++) {
            int row = rg * 2 + rr;
            int o = (rowBase + row) * 256 + gcol;
            float m  = Cx[0][row][col];
            float lv = tanhf(Cx[1][row][col]);
            float iv = 0.5f * expf(-lv);      // 1/(2*exp(logvar))
            float yv = y[o];
            float zv = z[o];
            float Mt = mA - 2.f * m * mB + 2.f * m * m;
            float dy = m - yv, dz = m - zv;
            float term = iv * (Mt - dy * dy - dz * dz);
#pragma unroll
            for (int msk = 8; msk; msk >>= 1)
                term += __shfl_xor(term, msk, 16);
            if (col == 0) atomicAdd(&rowAcc[rowBase + row], term);  // no fence
        }
    }
}

// ---------------------------------------------------------------------------
// K3: 1 block. out = mean_i relu(rowAcc[i]).
// ---------------------------------------------------------------------------
__global__ __launch_bounds__(256)
void k3_final(const float* __restrict__ rowAcc, float* __restrict__ out) {
    __shared__ float red[4];
    int t = threadIdx.x, lane = t & 63, wave = t >> 6;
    float v = 0.f;
#pragma unroll
    for (int p = 0; p < 4; p++)
        v += fmaxf(rowAcc[p * 256 + t], 0.f);
#pragma unroll
    for (int msk = 32; msk; msk >>= 1)
        v += __shfl_xor(v, msk, 64);
    if (lane == 0) red[wave] = v;
    __syncthreads();
    if (t == 0)
        out[0] = (red[0] + red[1] + red[2] + red[3]) * (1.f / 1024.f);
}

// ---------------------------------------------------------------------------
extern "C" void kernel_launch(void* const* d_in, const int* in_sizes, int n_in,
                              void* d_out, int out_size, void* d_ws, size_t ws_size,
                              hipStream_t stream) {
    const float* x   = (const float*)d_in[0];
    const float* y   = (const float*)d_in[1];
    const float* zs  = (const float*)d_in[2];
    const float* w1m = (const float*)d_in[3];
    const float* b1m = (const float*)d_in[4];
    const float* w2m = (const float*)d_in[5];
    const float* b2m = (const float*)d_in[6];
    const float* w1l = (const float*)d_in[7];
    const float* b1l = (const float*)d_in[8];
    const float* w2l = (const float*)d_in[9];
    const float* b2l = (const float*)d_in[10];
    float* out = (float*)d_out;

    char* ws = (char*)d_ws;
    float* pA1    = (float*)(ws);                      // 16x256 f32 = 16 KB
    float* pB1    = (float*)(ws + (256u << 10));       // 16 KB
    float* rowAcc = (float*)(ws + (512u << 10));       // 4 KB
    unsigned short* hmH = (unsigned short*)(ws + (1024u << 10));  // 512 KB each
    unsigned short* hmL = (unsigned short*)(ws + (1536u << 10));
    unsigned short* hlH = (unsigned short*)(ws + (2048u << 10));
    unsigned short* hlL = (unsigned short*)(ws + (2560u << 10));
    unsigned short* w2mH = (unsigned short*)(ws + (3072u << 10)); // 128 KB each
    unsigned short* w2mL = (unsigned short*)(ws + (3200u << 10));
    unsigned short* w2lH = (unsigned short*)(ws + (3328u << 10));
    unsigned short* w2lL = (unsigned short*)(ws + (3456u << 10));

    k1_layer1<<<528, 256, 0, stream>>>(x, w1m, w1l, b1m, b1l, w2m, w2l,
                                       hmH, hmL, hlH, hlL,
                                       w2mH, w2mL, w2lH, w2lL,
                                       y, zs, pA1, pB1, rowAcc);
    k2_fused<<<512, 256, 0, stream>>>(hmH, hmL, hlH, hlL,
                                      w2mH, w2mL, w2lH, w2lL,
                                      b2m, b2l, y, zs, pA1, pB1, rowAcc);
    k3_final<<<1, 256, 0, stream>>>(rowAcc, out);
}